// Round 2
// baseline (24185.577 us; speedup 1.0000x reference)
//
#include <hip/hip_runtime.h>

typedef __attribute__((ext_vector_type(8))) short short8;
typedef __attribute__((ext_vector_type(4))) float f32x4;
typedef __attribute__((ext_vector_type(4))) unsigned short u16x4;
typedef unsigned short ushort;

#define MFMA16(a,b,c) __builtin_amdgcn_mfma_f32_16x16x32_bf16((a),(b),(c),0,0,0)

static __device__ __forceinline__ float bf2f(ushort u){
  union { unsigned int i; float f; } z; z.i = ((unsigned int)u) << 16; return z.f;
}
static __device__ __forceinline__ ushort f2bf(float f){
  union { float f; unsigned int i; } z; z.f = f;
  unsigned int x = z.i;
  unsigned int r = (x + 0x7fffu + ((x >> 16) & 1u)) >> 16;   // RNE
  return (ushort)r;
}

// ---------------------------------------------------------------------------
// fp32 -> bf16 convert, 4 elems/thread, exact grids (n % 4 == 0)
// ---------------------------------------------------------------------------
__global__ __launch_bounds__(256) void cvt_k(
    const float* __restrict__ in, ushort* __restrict__ out, int n)
{
  int i = (blockIdx.x * 256 + threadIdx.x) * 4;
  if (i < n){
    float4 v = *(const float4*)(in + i);
    u16x4 o = { f2bf(v.x), f2bf(v.y), f2bf(v.z), f2bf(v.w) };
    *(u16x4*)(out + i) = o;
  }
}

// ---------------------------------------------------------------------------
// GEMM: C[M,N] = A[M,K](bf16) @ B[K,N](bf16) + bias[N](fp32).
// C is bf16 (F32OUT=0) or fp32 (F32OUT=1). M%64==0, N%64==0, K%32==0.
// Block=256 (4 waves), BM=BN=64, BK=32. B staged transposed in LDS
// [col][k] pitch 40 with XOR swizzle on the k-block.
// ---------------------------------------------------------------------------
template<int F32OUT>
__global__ __launch_bounds__(256) void gemm_bias_k(
    const ushort* __restrict__ A,
    const ushort* __restrict__ B,
    const float*  __restrict__ bias,
    void* __restrict__ Cv,
    int M, int N, int K)
{
  __shared__ __align__(16) ushort Blds[64 * 40];
  const int tid  = threadIdx.x;
  const int wid  = tid >> 6;
  const int lane = tid & 63;
  const int quad = lane >> 4;
  const int lc   = lane & 15;
  const int nb   = N >> 6;
  const int bn   = (blockIdx.x % nb) << 6;
  const int bm   = (blockIdx.x / nb) << 6;

  const int sk  = tid >> 3;   // 0..31 : k within BK
  const int scg = tid & 7;    // col group (8 cols each)

  f32x4 acc[4] = {{0,0,0,0},{0,0,0,0},{0,0,0,0},{0,0,0,0}};
  const int arow = bm + wid * 16 + lc;
  const ushort* aptr = A + (size_t)arow * K + quad * 8;

  for (int k0 = 0; k0 < K; k0 += 32){
    short8 bv = *(const short8*)(B + (size_t)(k0 + sk) * N + bn + (scg << 3));
    #pragma unroll
    for (int i = 0; i < 8; ++i){
      int c = (scg << 3) + i;
      int p = c * 40 + (((sk >> 3) ^ (scg & 3)) << 3) + (sk & 7);
      Blds[p] = (ushort)bv[i];
    }
    __syncthreads();
    short8 av = *(const short8*)(aptr + k0);
    #pragma unroll
    for (int nt = 0; nt < 4; ++nt){
      int c2 = (nt << 4) + lc;
      int p  = c2 * 40 + ((quad ^ ((c2 >> 3) & 3)) << 3);
      short8 bfrag = *(const short8*)(Blds + p);
      acc[nt] = MFMA16(av, bfrag, acc[nt]);
    }
    __syncthreads();
  }
  #pragma unroll
  for (int nt = 0; nt < 4; ++nt){
    #pragma unroll
    for (int i = 0; i < 4; ++i){
      int m = bm + wid * 16 + quad * 4 + i;   // C/D: row=(lane>>4)*4+reg, col=lane&15
      int n = bn + (nt << 4) + lc;
      float v = acc[nt][i] + bias[n];
      if (F32OUT) ((float*)Cv)[(size_t)m * N + n] = v;
      else        ((ushort*)Cv)[(size_t)m * N + n] = f2bf(v);
    }
  }
}

// ---------------------------------------------------------------------------
// Persistent GRU recurrence. 32 WGs x 384 threads. WG g owns units [16g,16g+16).
// R slice (cols {u, 512+u, 1024+u}) pre-packed as MFMA B-frags in VGPRs.
// Wave roles: gate = wid%3 (z,r,h), mtile = wid/3 (batch 0-15 / 16-31).
// hc[t] = bf16 carried-state history (write-once per t). cnt[t] = arrival flags.
// ---------------------------------------------------------------------------
#define REC_G 32

__global__ __launch_bounds__(384) void rec_k(
    const ushort* __restrict__ xw,    // [32768,1536] bf16, row = b*1024+t
    const ushort* __restrict__ R,     // [512,1536] bf16
    const float*  __restrict__ brec,  // [1536] fp32
    const float*  __restrict__ h0,    // [512] fp32 (tiled over batch)
    ushort* __restrict__ out,         // [32768,512] bf16 h_new (pre-zoneout)
    ushort* __restrict__ hc,          // [1024*32*512] bf16 carried state
    int* __restrict__ cnt)            // [1024]
{
  __shared__ float m_lds[3][32][17];
  __shared__ float brec_l[48];
  const int tid  = threadIdx.x;
  const int wid  = tid >> 6;
  const int lane = tid & 63;
  const int quad = lane >> 4;
  const int lc   = lane & 15;
  const int g    = blockIdx.x;
  const int ug0  = g << 4;
  const int gate = wid % 3, mtile = wid / 3;
  const int col0 = (gate << 9) + ug0;

  // ---- preload R fragments into registers (64 VGPRs) ----
  short8 bfrag[16];
  #pragma unroll
  for (int f = 0; f < 16; ++f){
    short8 v;
    #pragma unroll
    for (int j = 0; j < 8; ++j)
      v[j] = (short)R[(size_t)(f * 32 + quad * 8 + j) * 1536 + col0 + lc];
    bfrag[f] = v;
  }
  if (tid < 48) brec_l[tid] = brec[(tid >> 4) * 512 + ug0 + (tid & 15)];

  // ---- epilogue item ownership: item0 = tid, item1 = tid+384 (tid<128) ----
  const int  b0i  = tid >> 4;
  const int  u0   = tid & 15;
  const int  b1i  = (tid + 384) >> 4;          // (tid+384)&15 == u0
  const bool has1 = (tid < 128);
  float hp0 = h0[ug0 + u0];
  float hp1 = hp0;

  // ---- prefetch xw for t=0 ----
  ushort xz0, xr0, xh0, xz1 = 0, xr1 = 0, xh1 = 0;
  {
    size_t r0_ = ((size_t)b0i * 1024 + 0) * 1536 + ug0 + u0;
    xz0 = xw[r0_]; xr0 = xw[r0_ + 512]; xh0 = xw[r0_ + 1024];
    if (has1){
      size_t r1_ = ((size_t)b1i * 1024 + 0) * 1536 + ug0 + u0;
      xz1 = xw[r1_]; xr1 = xw[r1_ + 512]; xh1 = xw[r1_ + 1024];
    }
  }
  __syncthreads();

  long budget = 60000000L;  // spin safety valve: degrade, don't hang
  for (int t = 0; t < 1024; ++t){
    // prefetch next step's xw (independent of flags -> hides HBM latency)
    ushort nz0 = 0, nr0 = 0, nh0 = 0, nz1 = 0, nr1 = 0, nh1 = 0;
    if (t < 1023){
      size_t r0_ = ((size_t)b0i * 1024 + (t + 1)) * 1536 + ug0 + u0;
      nz0 = xw[r0_]; nr0 = xw[r0_ + 512]; nh0 = xw[r0_ + 1024];
      if (has1){
        size_t r1_ = ((size_t)b1i * 1024 + (t + 1)) * 1536 + ug0 + u0;
        nz1 = xw[r1_]; nr1 = xw[r1_ + 512]; nh1 = xw[r1_ + 1024];
      }
    }
    if (t > 0){
      if (tid == 0){
        while (budget > 0 &&
               __hip_atomic_load(cnt + (t - 1), __ATOMIC_RELAXED,
                                 __HIP_MEMORY_SCOPE_AGENT) < REC_G){
          __builtin_amdgcn_s_sleep(1);
          --budget;
        }
      }
      __syncthreads();
      __threadfence();   // agent acquire: invalidate stale caches before hc reads
    }

    // ---- m = h_{t-1} @ R_slice via MFMA (A-frag: A[m=lane&15][k=quad*8+j]) ----
    f32x4 acc0 = {0,0,0,0}, acc1 = {0,0,0,0};
    if (t == 0){
      #pragma unroll
      for (int f = 0; f < 16; ++f){
        short8 av;
        #pragma unroll
        for (int j = 0; j < 8; ++j)
          av[j] = (short)f2bf(h0[f * 32 + quad * 8 + j]);  // broadcast row
        if (f & 1) acc1 = MFMA16(av, bfrag[f], acc1);
        else       acc0 = MFMA16(av, bfrag[f], acc0);
      }
    } else {
      const ushort* hrow =
          hc + (size_t)(t - 1) * 16384 + (size_t)(mtile * 16 + lc) * 512 + quad * 8;
      #pragma unroll
      for (int f = 0; f < 16; ++f){
        short8 av = *(const short8*)(hrow + f * 32);
        if (f & 1) acc1 = MFMA16(av, bfrag[f], acc1);
        else       acc0 = MFMA16(av, bfrag[f], acc0);
      }
    }
    f32x4 acc = acc0 + acc1;
    #pragma unroll
    for (int i = 0; i < 4; ++i)
      m_lds[gate][(mtile << 4) + (quad << 2) + i][lc] = acc[i];
    __syncthreads();

    // ---- gate math (fp32), zoneout on carried state only ----
    {
      float mz = m_lds[0][b0i][u0] + brec_l[u0];
      float mr = m_lds[1][b0i][u0] + brec_l[16 + u0];
      float mh = m_lds[2][b0i][u0] + brec_l[32 + u0];
      float z  = 1.f / (1.f + __expf(-(bf2f(xz0) + mz)));
      float r  = 1.f / (1.f + __expf(-(bf2f(xr0) + mr)));
      float ax = bf2f(xh0) + r * mh;
      float hh = 1.f - 2.f / (1.f + __expf(2.f * ax));
      float hn = z * hp0 + (1.f - z) * hh;
      float hcar = hn + 0.1f * (hp0 - hn);
      out[((size_t)b0i * 1024 + t) * 512 + ug0 + u0] = f2bf(hn);
      hc[(size_t)t * 16384 + (size_t)b0i * 512 + ug0 + u0] = f2bf(hcar);
      hp0 = hcar;
    }
    if (has1){
      float mz = m_lds[0][b1i][u0] + brec_l[u0];
      float mr = m_lds[1][b1i][u0] + brec_l[16 + u0];
      float mh = m_lds[2][b1i][u0] + brec_l[32 + u0];
      float z  = 1.f / (1.f + __expf(-(bf2f(xz1) + mz)));
      float r  = 1.f / (1.f + __expf(-(bf2f(xr1) + mr)));
      float ax = bf2f(xh1) + r * mh;
      float hh = 1.f - 2.f / (1.f + __expf(2.f * ax));
      float hn = z * hp1 + (1.f - z) * hh;
      float hcar = hn + 0.1f * (hp1 - hn);
      out[((size_t)b1i * 1024 + t) * 512 + ug0 + u0] = f2bf(hn);
      hc[(size_t)t * 16384 + (size_t)b1i * 512 + ug0 + u0] = f2bf(hcar);
      hp1 = hcar;
    }
    xz0 = nz0; xr0 = nr0; xh0 = nh0;
    xz1 = nz1; xr1 = nr1; xh1 = nh1;
    __syncthreads();   // drains this WG's hc stores before the release below
    if (tid == 0)
      __hip_atomic_fetch_add(cnt + t, 1, __ATOMIC_RELEASE, __HIP_MEMORY_SCOPE_AGENT);
  }
}

// ---------------------------------------------------------------------------
// out = base + a[i1]*p1 (+ a[i2]*p2 if p2 != null), bf16 in/out, fp32 a
// ---------------------------------------------------------------------------
__global__ __launch_bounds__(256) void combine_k(
    const ushort* __restrict__ base,
    const ushort* __restrict__ p1,
    const ushort* __restrict__ p2,
    const float*  __restrict__ avec,
    int i1, int i2,
    ushort* __restrict__ outp)
{
  size_t idx = (((size_t)blockIdx.x * 256) + threadIdx.x) << 3;
  float a1 = avec[i1];
  float a2 = 0.f;
  short8 vb = *(const short8*)(base + idx);
  short8 v1 = *(const short8*)(p1 + idx);
  short8 v2 = {0,0,0,0,0,0,0,0};
  if (p2 != nullptr){ a2 = avec[i2]; v2 = *(const short8*)(p2 + idx); }
  short8 o;
  #pragma unroll
  for (int j = 0; j < 8; ++j){
    float f = bf2f((ushort)vb[j]) + a1 * bf2f((ushort)v1[j]);
    if (p2 != nullptr) f += a2 * bf2f((ushort)v2[j]);
    o[j] = (short)f2bf(f);
  }
  *(short8*)(outp + idx) = o;
}

// ---------------------------------------------------------------------------
extern "C" void kernel_launch(void* const* d_in, const int* in_sizes, int n_in,
                              void* d_out, int out_size, void* d_ws, size_t ws_size,
                              hipStream_t stream)
{
  const float* x   = (const float*)d_in[0];   // [32,1024,256]
  const float* k0  = (const float*)d_in[1];   // [256,1536]
  const float* r0  = (const float*)d_in[2];   // [512,1536]
  const float* b0  = (const float*)d_in[3];   // [2,1536]
  const float* ks  = (const float*)d_in[4];
  const float* rs  = (const float*)d_in[5];
  const float* bs  = (const float*)d_in[6];
  const float* h00 = (const float*)d_in[7];   // [1,512]
  const float* h01 = (const float*)d_in[8];
  const float* h02 = (const float*)d_in[9];
  const float* a   = (const float*)d_in[10];  // [3]
  const float* wd  = (const float*)d_in[11];  // [512,256]
  const float* bd  = (const float*)d_in[12];  // [256]
  float* outp = (float*)d_out;                // [32,1024,256] fp32

  // ws layout (bytes), total ~240.7 MB:
  //   [0,        100663296)  XW    [32768,1536] bf16 (also final combined A)
  //   [100663296,134217728)  out0  [32768,512] bf16
  //   [134217728,167772160)  pred0
  //   [167772160,201326592)  pred1 (first 16.8MB aliases x_bf, then combined A2)
  //   [201326592,234881024)  hc history [1024,32,512] bf16
  //   [234881024,...]        bf16 weights: k0b,r0b,ksb,rsb,wdb; then cnt[3][1024]
  char* ws = (char*)d_ws;
  ushort* XW    = (ushort*)(ws);
  ushort* out0  = (ushort*)(ws + 100663296u);
  ushort* pred0 = (ushort*)(ws + 134217728u);
  ushort* pred1 = (ushort*)(ws + 167772160u);
  ushort* hcb   = (ushort*)(ws + 201326592u);
  ushort* xbf   = pred1;                       // alias: dead before combine #1
  ushort* k0b   = (ushort*)(ws + 234881024u);            //  786432 B
  ushort* r0b   = (ushort*)(ws + 234881024u + 786432u);  // 1572864 B
  ushort* ksb   = (ushort*)(ws + 234881024u + 2359296u); // 1572864 B
  ushort* rsb   = (ushort*)(ws + 234881024u + 3932160u); // 1572864 B
  ushort* wdb   = (ushort*)(ws + 234881024u + 5505024u); //  262144 B
  int*    cnt   = (int*)   (ws + 234881024u + 5767168u); //   12288 B

  hipMemsetAsync(cnt, 0, 3 * 1024 * sizeof(int), stream);

  dim3 blk(256);
  // fp32 -> bf16 converts (grids exact: n/1024)
  cvt_k<<<dim3(8192), blk, 0, stream>>>(x,  xbf, 8388608);
  cvt_k<<<dim3(384),  blk, 0, stream>>>(k0, k0b, 393216);
  cvt_k<<<dim3(768),  blk, 0, stream>>>(r0, r0b, 786432);
  cvt_k<<<dim3(768),  blk, 0, stream>>>(ks, ksb, 786432);
  cvt_k<<<dim3(768),  blk, 0, stream>>>(rs, rsb, 786432);
  cvt_k<<<dim3(128),  blk, 0, stream>>>(wd, wdb, 131072);

  // Layer 0
  gemm_bias_k<0><<<dim3(512 * 24), blk, 0, stream>>>(xbf, k0b, b0, XW, 32768, 1536, 256);
  rec_k<<<dim3(REC_G), dim3(384), 0, stream>>>(XW, r0b, b0 + 1536, h00, out0, hcb, cnt);
  // Skip GRU #1: input = out0
  gemm_bias_k<0><<<dim3(512 * 24), blk, 0, stream>>>(out0, ksb, bs, XW, 32768, 1536, 512);
  rec_k<<<dim3(REC_G), dim3(384), 0, stream>>>(XW, rsb, bs + 1536, h01, pred0, hcb, cnt + 1024);
  // Skip GRU #2: input = out0 + a[0]*pred0 (built in pred1's slot; x_bf dead)
  combine_k<<<dim3(8192), blk, 0, stream>>>(out0, pred0, nullptr, a, 0, 0, pred1);
  gemm_bias_k<0><<<dim3(512 * 24), blk, 0, stream>>>(pred1, ksb, bs, XW, 32768, 1536, 512);
  rec_k<<<dim3(REC_G), dim3(384), 0, stream>>>(XW, rsb, bs + 1536, h02, pred1, hcb, cnt + 2048);
  // Final: (out0 + a[1]*pred0 + a[2]*pred1) @ wd + bd  -> fp32 d_out
  combine_k<<<dim3(8192), blk, 0, stream>>>(out0, pred0, pred1, a, 1, 2, XW);
  gemm_bias_k<1><<<dim3(512 * 4), blk, 0, stream>>>(XW, wdb, bd, outp, 32768, 256, 512);
}

// Round 3
// 22941.801 us; speedup vs baseline: 1.0542x; 1.0542x over previous
//
#include <hip/hip_runtime.h>

typedef __attribute__((ext_vector_type(8))) short short8;
typedef __attribute__((ext_vector_type(4))) float f32x4;
typedef __attribute__((ext_vector_type(4))) unsigned short u16x4;
typedef unsigned short ushort;

#define MFMA16(a,b,c) __builtin_amdgcn_mfma_f32_16x16x32_bf16((a),(b),(c),0,0,0)

static __device__ __forceinline__ float bf2f(ushort u){
  union { unsigned int i; float f; } z; z.i = ((unsigned int)u) << 16; return z.f;
}
static __device__ __forceinline__ ushort f2bf(float f){
  union { float f; unsigned int i; } z; z.f = f;
  unsigned int x = z.i;
  unsigned int r = (x + 0x7fffu + ((x >> 16) & 1u)) >> 16;   // RNE
  return (ushort)r;
}

// 16B coherence-point load (2x u64 agent atomics -> global_load_dwordx2 sc0 sc1)
static __device__ __forceinline__ short8 ld_hc16(const ushort* p){
  union { unsigned long long q[2]; short8 v; } u;
  u.q[0] = __hip_atomic_load((const unsigned long long*)p,
                             __ATOMIC_RELAXED, __HIP_MEMORY_SCOPE_AGENT);
  u.q[1] = __hip_atomic_load((const unsigned long long*)(p + 4),
                             __ATOMIC_RELAXED, __HIP_MEMORY_SCOPE_AGENT);
  return u.v;
}
// 2B write-through store (bypasses L1/L2 -> coherence point)
static __device__ __forceinline__ void st_hc2(ushort* p, ushort v){
  unsigned int vv = v;
  asm volatile("global_store_short %0, %1, off sc0 sc1" :: "v"(p), "v"(vv) : "memory");
}

// ---------------------------------------------------------------------------
// fp32 -> bf16 convert, 4 elems/thread
// ---------------------------------------------------------------------------
__global__ __launch_bounds__(256) void cvt_k(
    const float* __restrict__ in, ushort* __restrict__ out, int n)
{
  int i = (blockIdx.x * 256 + threadIdx.x) * 4;
  if (i < n){
    float4 v = *(const float4*)(in + i);
    u16x4 o = { f2bf(v.x), f2bf(v.y), f2bf(v.z), f2bf(v.w) };
    *(u16x4*)(out + i) = o;
  }
}

// ---------------------------------------------------------------------------
// GEMM: C[M,N] = A[M,K](bf16) @ B[K,N](bf16) + bias[N](fp32).
// ---------------------------------------------------------------------------
template<int F32OUT>
__global__ __launch_bounds__(256) void gemm_bias_k(
    const ushort* __restrict__ A,
    const ushort* __restrict__ B,
    const float*  __restrict__ bias,
    void* __restrict__ Cv,
    int M, int N, int K)
{
  __shared__ __align__(16) ushort Blds[64 * 40];
  const int tid  = threadIdx.x;
  const int wid  = tid >> 6;
  const int lane = tid & 63;
  const int quad = lane >> 4;
  const int lc   = lane & 15;
  const int nb   = N >> 6;
  const int bn   = (blockIdx.x % nb) << 6;
  const int bm   = (blockIdx.x / nb) << 6;

  const int sk  = tid >> 3;
  const int scg = tid & 7;

  f32x4 acc[4] = {{0,0,0,0},{0,0,0,0},{0,0,0,0},{0,0,0,0}};
  const int arow = bm + wid * 16 + lc;
  const ushort* aptr = A + (size_t)arow * K + quad * 8;

  for (int k0 = 0; k0 < K; k0 += 32){
    short8 bv = *(const short8*)(B + (size_t)(k0 + sk) * N + bn + (scg << 3));
    #pragma unroll
    for (int i = 0; i < 8; ++i){
      int c = (scg << 3) + i;
      int p = c * 40 + (((sk >> 3) ^ (scg & 3)) << 3) + (sk & 7);
      Blds[p] = (ushort)bv[i];
    }
    __syncthreads();
    short8 av = *(const short8*)(aptr + k0);
    #pragma unroll
    for (int nt = 0; nt < 4; ++nt){
      int c2 = (nt << 4) + lc;
      int p  = c2 * 40 + ((quad ^ ((c2 >> 3) & 3)) << 3);
      short8 bfrag = *(const short8*)(Blds + p);
      acc[nt] = MFMA16(av, bfrag, acc[nt]);
    }
    __syncthreads();
  }
  #pragma unroll
  for (int nt = 0; nt < 4; ++nt){
    #pragma unroll
    for (int i = 0; i < 4; ++i){
      int m = bm + wid * 16 + quad * 4 + i;
      int n = bn + (nt << 4) + lc;
      float v = acc[nt][i] + bias[n];
      if (F32OUT) ((float*)Cv)[(size_t)m * N + n] = v;
      else        ((ushort*)Cv)[(size_t)m * N + n] = f2bf(v);
    }
  }
}

// ---------------------------------------------------------------------------
// Persistent GRU recurrence. 32 WGs x 384 threads. WG g owns units [16g,16g+16).
// Fence-free protocol: hc ring[4] exchanged via sc0/sc1 per-access coherence;
// per-(t,g) flags (value = layer lval) polled by wave 0 with ballot.
// ---------------------------------------------------------------------------
#define REC_G 32

__global__ __launch_bounds__(384) void rec_k(
    const ushort* __restrict__ xw,    // [32768,1536] bf16, row = b*1024+t
    const ushort* __restrict__ R,     // [512,1536] bf16
    const float*  __restrict__ brec,  // [1536] fp32
    const float*  __restrict__ h0,    // [512] fp32 (tiled over batch)
    ushort* __restrict__ out,         // [32768,512] bf16 h_new (pre-zoneout)
    ushort* __restrict__ hc,          // ring [4][32][512] bf16 carried state
    int* __restrict__ flags,          // [1024][32]
    int lval)                         // layer+1
{
  __shared__ float m_lds[3][32][17];
  __shared__ float brec_l[48];
  const int tid  = threadIdx.x;
  const int wid  = tid >> 6;
  const int lane = tid & 63;
  const int quad = lane >> 4;
  const int lc   = lane & 15;
  const int g    = blockIdx.x;
  const int ug0  = g << 4;
  const int gate = wid % 3, mtile = wid / 3;
  const int col0 = (gate << 9) + ug0;

  // ---- preload R fragments into registers (64 VGPRs) ----
  short8 bfrag[16];
  #pragma unroll
  for (int f = 0; f < 16; ++f){
    short8 v;
    #pragma unroll
    for (int j = 0; j < 8; ++j)
      v[j] = (short)R[(size_t)(f * 32 + quad * 8 + j) * 1536 + col0 + lc];
    bfrag[f] = v;
  }
  if (tid < 48) brec_l[tid] = brec[(tid >> 4) * 512 + ug0 + (tid & 15)];

  // ---- epilogue item ownership: item0 = tid, item1 = tid+384 (tid<128) ----
  const int  b0i  = tid >> 4;
  const int  u0   = tid & 15;
  const int  b1i  = (tid + 384) >> 4;
  const bool has1 = (tid < 128);
  float hp0 = h0[ug0 + u0];
  float hp1 = hp0;

  // ---- prefetch xw for t=0 ----
  ushort xz0, xr0, xh0, xz1 = 0, xr1 = 0, xh1 = 0;
  {
    size_t r0_ = ((size_t)b0i * 1024 + 0) * 1536 + ug0 + u0;
    xz0 = xw[r0_]; xr0 = xw[r0_ + 512]; xh0 = xw[r0_ + 1024];
    if (has1){
      size_t r1_ = ((size_t)b1i * 1024 + 0) * 1536 + ug0 + u0;
      xz1 = xw[r1_]; xr1 = xw[r1_ + 512]; xh1 = xw[r1_ + 1024];
    }
  }
  __syncthreads();

  long budget = 5000000L;   // spin safety valve: degrade, don't hang
  for (int t = 0; t < 1024; ++t){
    // prefetch next step's xw (independent of flags -> hides HBM latency)
    ushort nz0 = 0, nr0 = 0, nh0 = 0, nz1 = 0, nr1 = 0, nh1 = 0;
    if (t < 1023){
      size_t r0_ = ((size_t)b0i * 1024 + (t + 1)) * 1536 + ug0 + u0;
      nz0 = xw[r0_]; nr0 = xw[r0_ + 512]; nh0 = xw[r0_ + 1024];
      if (has1){
        size_t r1_ = ((size_t)b1i * 1024 + (t + 1)) * 1536 + ug0 + u0;
        nz1 = xw[r1_]; nr1 = xw[r1_ + 512]; nh1 = xw[r1_ + 1024];
      }
    }
    if (t > 0){
      if (wid == 0){
        const int* fp = flags + (size_t)(t - 1) * REC_G + (lane & 31);
        while (budget > 0){
          int v = __hip_atomic_load(fp, __ATOMIC_RELAXED, __HIP_MEMORY_SCOPE_AGENT);
          if (__ballot(v >= lval) == ~0ull) break;
          --budget;
        }
      }
      __syncthreads();   // B: all waves see flags satisfied
    }

    // ---- m = h_{t-1} @ R_slice via MFMA ----
    f32x4 acc0 = {0,0,0,0}, acc1 = {0,0,0,0};
    if (t == 0){
      #pragma unroll
      for (int f = 0; f < 16; ++f){
        short8 av;
        #pragma unroll
        for (int j = 0; j < 8; ++j)
          av[j] = (short)f2bf(h0[f * 32 + quad * 8 + j]);
        if (f & 1) acc1 = MFMA16(av, bfrag[f], acc1);
        else       acc0 = MFMA16(av, bfrag[f], acc0);
      }
    } else {
      const ushort* hrow =
          hc + ((t - 1) & 3) * 16384 + (size_t)(mtile * 16 + lc) * 512 + quad * 8;
      short8 av[16];
      #pragma unroll
      for (int f = 0; f < 16; ++f) av[f] = ld_hc16(hrow + f * 32);  // all in flight
      #pragma unroll
      for (int f = 0; f < 16; ++f){
        if (f & 1) acc1 = MFMA16(av[f], bfrag[f], acc1);
        else       acc0 = MFMA16(av[f], bfrag[f], acc0);
      }
    }
    f32x4 acc = acc0 + acc1;
    #pragma unroll
    for (int i = 0; i < 4; ++i)
      m_lds[gate][(mtile << 4) + (quad << 2) + i][lc] = acc[i];
    __syncthreads();   // C

    // ---- gate math (fp32), zoneout on carried state only ----
    ushort hn0s, hn1s = 0;
    {
      float mz = m_lds[0][b0i][u0] + brec_l[u0];
      float mr = m_lds[1][b0i][u0] + brec_l[16 + u0];
      float mh = m_lds[2][b0i][u0] + brec_l[32 + u0];
      float z  = 1.f / (1.f + __expf(-(bf2f(xz0) + mz)));
      float r  = 1.f / (1.f + __expf(-(bf2f(xr0) + mr)));
      float ax = bf2f(xh0) + r * mh;
      float hh = 1.f - 2.f / (1.f + __expf(2.f * ax));
      float hn = z * hp0 + (1.f - z) * hh;
      float hcar = hn + 0.1f * (hp0 - hn);
      hn0s = f2bf(hn);
      st_hc2(hc + (t & 3) * 16384 + b0i * 512 + ug0 + u0, f2bf(hcar));
      hp0 = hcar;
    }
    if (has1){
      float mz = m_lds[0][b1i][u0] + brec_l[u0];
      float mr = m_lds[1][b1i][u0] + brec_l[16 + u0];
      float mh = m_lds[2][b1i][u0] + brec_l[32 + u0];
      float z  = 1.f / (1.f + __expf(-(bf2f(xz1) + mz)));
      float r  = 1.f / (1.f + __expf(-(bf2f(xr1) + mr)));
      float ax = bf2f(xh1) + r * mh;
      float hh = 1.f - 2.f / (1.f + __expf(2.f * ax));
      float hn = z * hp1 + (1.f - z) * hh;
      float hcar = hn + 0.1f * (hp1 - hn);
      hn1s = f2bf(hn);
      st_hc2(hc + (t & 3) * 16384 + b1i * 512 + ug0 + u0, f2bf(hcar));
      hp1 = hcar;
    }
    asm volatile("s_waitcnt vmcnt(0)" ::: "memory");  // hc stores at coherence pt
    __syncthreads();   // A: whole WG's hc stores drained
    if (tid == 0)
      __hip_atomic_store(flags + (size_t)t * REC_G + g, lval,
                         __ATOMIC_RELAXED, __HIP_MEMORY_SCOPE_AGENT);
    // out stores AFTER publish: their drain is off the critical path
    out[((size_t)b0i * 1024 + t) * 512 + ug0 + u0] = hn0s;
    if (has1) out[((size_t)b1i * 1024 + t) * 512 + ug0 + u0] = hn1s;

    xz0 = nz0; xr0 = nr0; xh0 = nh0;
    xz1 = nz1; xr1 = nr1; xh1 = nh1;
  }
}

// ---------------------------------------------------------------------------
// out = base + a[i1]*p1 (+ a[i2]*p2 if p2 != null)
// ---------------------------------------------------------------------------
__global__ __launch_bounds__(256) void combine_k(
    const ushort* __restrict__ base,
    const ushort* __restrict__ p1,
    const ushort* __restrict__ p2,
    const float*  __restrict__ avec,
    int i1, int i2,
    ushort* __restrict__ outp)
{
  size_t idx = (((size_t)blockIdx.x * 256) + threadIdx.x) << 3;
  float a1 = avec[i1];
  float a2 = 0.f;
  short8 vb = *(const short8*)(base + idx);
  short8 v1 = *(const short8*)(p1 + idx);
  short8 v2 = {0,0,0,0,0,0,0,0};
  if (p2 != nullptr){ a2 = avec[i2]; v2 = *(const short8*)(p2 + idx); }
  short8 o;
  #pragma unroll
  for (int j = 0; j < 8; ++j){
    float f = bf2f((ushort)vb[j]) + a1 * bf2f((ushort)v1[j]);
    if (p2 != nullptr) f += a2 * bf2f((ushort)v2[j]);
    o[j] = (short)f2bf(f);
  }
  *(short8*)(outp + idx) = o;
}

// ---------------------------------------------------------------------------
extern "C" void kernel_launch(void* const* d_in, const int* in_sizes, int n_in,
                              void* d_out, int out_size, void* d_ws, size_t ws_size,
                              hipStream_t stream)
{
  const float* x   = (const float*)d_in[0];
  const float* k0  = (const float*)d_in[1];
  const float* r0  = (const float*)d_in[2];
  const float* b0  = (const float*)d_in[3];
  const float* ks  = (const float*)d_in[4];
  const float* rs  = (const float*)d_in[5];
  const float* bs  = (const float*)d_in[6];
  const float* h00 = (const float*)d_in[7];
  const float* h01 = (const float*)d_in[8];
  const float* h02 = (const float*)d_in[9];
  const float* a   = (const float*)d_in[10];
  const float* wd  = (const float*)d_in[11];
  const float* bd  = (const float*)d_in[12];
  float* outp = (float*)d_out;

  // ws layout (bytes), total ~240.6 MB:
  //   [0,        100663296)  XW    [32768,1536] bf16 (also final combined A)
  //   [100663296,134217728)  out0  [32768,512] bf16
  //   [134217728,167772160)  pred0
  //   [167772160,201326592)  pred1 (first 16.8MB aliases x_bf)
  //   [201326592,201457664)  hc ring [4][32][512] bf16 (128KB)
  //   [201457664,201588736)  flags [1024][32] int (128KB, shared by layers)
  //   [234881024,...]        bf16 weights k0b,r0b,ksb,rsb,wdb
  char* ws = (char*)d_ws;
  ushort* XW    = (ushort*)(ws);
  ushort* out0  = (ushort*)(ws + 100663296u);
  ushort* pred0 = (ushort*)(ws + 134217728u);
  ushort* pred1 = (ushort*)(ws + 167772160u);
  ushort* hcb   = (ushort*)(ws + 201326592u);
  int*    flags = (int*)   (ws + 201457664u);
  ushort* xbf   = pred1;
  ushort* k0b   = (ushort*)(ws + 234881024u);
  ushort* r0b   = (ushort*)(ws + 234881024u + 786432u);
  ushort* ksb   = (ushort*)(ws + 234881024u + 2359296u);
  ushort* rsb   = (ushort*)(ws + 234881024u + 3932160u);
  ushort* wdb   = (ushort*)(ws + 234881024u + 5505024u);

  hipMemsetAsync(flags, 0, 1024 * REC_G * sizeof(int), stream);

  dim3 blk(256);
  cvt_k<<<dim3(8192), blk, 0, stream>>>(x,  xbf, 8388608);
  cvt_k<<<dim3(384),  blk, 0, stream>>>(k0, k0b, 393216);
  cvt_k<<<dim3(768),  blk, 0, stream>>>(r0, r0b, 786432);
  cvt_k<<<dim3(768),  blk, 0, stream>>>(ks, ksb, 786432);
  cvt_k<<<dim3(768),  blk, 0, stream>>>(rs, rsb, 786432);
  cvt_k<<<dim3(128),  blk, 0, stream>>>(wd, wdb, 131072);

  // Layer 0
  gemm_bias_k<0><<<dim3(512 * 24), blk, 0, stream>>>(xbf, k0b, b0, XW, 32768, 1536, 256);
  rec_k<<<dim3(REC_G), dim3(384), 0, stream>>>(XW, r0b, b0 + 1536, h00, out0, hcb, flags, 1);
  // Skip GRU #1: input = out0
  gemm_bias_k<0><<<dim3(512 * 24), blk, 0, stream>>>(out0, ksb, bs, XW, 32768, 1536, 512);
  rec_k<<<dim3(REC_G), dim3(384), 0, stream>>>(XW, rsb, bs + 1536, h01, pred0, hcb, flags, 2);
  // Skip GRU #2: input = out0 + a[0]*pred0
  combine_k<<<dim3(8192), blk, 0, stream>>>(out0, pred0, nullptr, a, 0, 0, pred1);
  gemm_bias_k<0><<<dim3(512 * 24), blk, 0, stream>>>(pred1, ksb, bs, XW, 32768, 1536, 512);
  rec_k<<<dim3(REC_G), dim3(384), 0, stream>>>(XW, rsb, bs + 1536, h02, pred1, hcb, flags, 3);
  // Final: (out0 + a[1]*pred0 + a[2]*pred1) @ wd + bd  -> fp32 d_out
  combine_k<<<dim3(8192), blk, 0, stream>>>(out0, pred0, pred1, a, 1, 2, XW);
  gemm_bias_k<1><<<dim3(512 * 4), blk, 0, stream>>>(XW, wdb, bd, outp, 32768, 256, 512);
}

// Round 4
// 14999.783 us; speedup vs baseline: 1.6124x; 1.5295x over previous
//
#include <hip/hip_runtime.h>

typedef __attribute__((ext_vector_type(8))) short short8;
typedef __attribute__((ext_vector_type(4))) float f32x4;
typedef __attribute__((ext_vector_type(4))) unsigned short u16x4;
typedef unsigned short ushort;

#define MFMA16(a,b,c) __builtin_amdgcn_mfma_f32_16x16x32_bf16((a),(b),(c),0,0,0)

static __device__ __forceinline__ float bf2f(ushort u){
  union { unsigned int i; float f; } z; z.i = ((unsigned int)u) << 16; return z.f;
}
static __device__ __forceinline__ ushort f2bf(float f){
  union { float f; unsigned int i; } z; z.f = f;
  unsigned int x = z.i;
  unsigned int r = (x + 0x7fffu + ((x >> 16) & 1u)) >> 16;   // RNE
  return (ushort)r;
}

// 16B coherence-point load (2x u64 agent atomics, bypass stale L1/L2)
static __device__ __forceinline__ short8 ld_hc16(const ushort* p){
  union { unsigned long long q[2]; short8 v; } u;
  u.q[0] = __hip_atomic_load((const unsigned long long*)p,
                             __ATOMIC_RELAXED, __HIP_MEMORY_SCOPE_AGENT);
  u.q[1] = __hip_atomic_load((const unsigned long long*)(p + 4),
                             __ATOMIC_RELAXED, __HIP_MEMORY_SCOPE_AGENT);
  return u.v;
}
// single bf16 from ring via aligned u32 agent atomic
static __device__ __forceinline__ float ld_ring_bf(const ushort* base, int idx){
  const unsigned int* p = (const unsigned int*)(base + (idx & ~1));
  unsigned int w = __hip_atomic_load(p, __ATOMIC_RELAXED, __HIP_MEMORY_SCOPE_AGENT);
  return bf2f((idx & 1) ? (ushort)(w >> 16) : (ushort)(w & 0xffffu));
}
// 2B write-through store to coherence point
static __device__ __forceinline__ void st_hc2(ushort* p, ushort v){
  unsigned int vv = v;
  asm volatile("global_store_short %0, %1, off sc0 sc1" :: "v"(p), "v"(vv) : "memory");
}

// ---------------------------------------------------------------------------
// fp32 -> bf16 convert, 4 elems/thread
// ---------------------------------------------------------------------------
__global__ __launch_bounds__(256) void cvt_k(
    const float* __restrict__ in, ushort* __restrict__ out, int n)
{
  int i = (blockIdx.x * 256 + threadIdx.x) * 4;
  if (i < n){
    float4 v = *(const float4*)(in + i);
    u16x4 o = { f2bf(v.x), f2bf(v.y), f2bf(v.z), f2bf(v.w) };
    *(u16x4*)(out + i) = o;
  }
}

// ---------------------------------------------------------------------------
// GEMM: C[M,N] = A[M,K](bf16) @ B[K,N](bf16) + bias[N](fp32).
// ---------------------------------------------------------------------------
template<int F32OUT>
__global__ __launch_bounds__(256) void gemm_bias_k(
    const ushort* __restrict__ A,
    const ushort* __restrict__ B,
    const float*  __restrict__ bias,
    void* __restrict__ Cv,
    int M, int N, int K)
{
  __shared__ __align__(16) ushort Blds[64 * 40];
  const int tid  = threadIdx.x;
  const int wid  = tid >> 6;
  const int lane = tid & 63;
  const int quad = lane >> 4;
  const int lc   = lane & 15;
  const int nb   = N >> 6;
  const int bn   = (blockIdx.x % nb) << 6;
  const int bm   = (blockIdx.x / nb) << 6;

  const int sk  = tid >> 3;
  const int scg = tid & 7;

  f32x4 acc[4] = {{0,0,0,0},{0,0,0,0},{0,0,0,0},{0,0,0,0}};
  const int arow = bm + wid * 16 + lc;
  const ushort* aptr = A + (size_t)arow * K + quad * 8;

  for (int k0 = 0; k0 < K; k0 += 32){
    short8 bv = *(const short8*)(B + (size_t)(k0 + sk) * N + bn + (scg << 3));
    #pragma unroll
    for (int i = 0; i < 8; ++i){
      int c = (scg << 3) + i;
      int p = c * 40 + (((sk >> 3) ^ (scg & 3)) << 3) + (sk & 7);
      Blds[p] = (ushort)bv[i];
    }
    __syncthreads();
    short8 av = *(const short8*)(aptr + k0);
    #pragma unroll
    for (int nt = 0; nt < 4; ++nt){
      int c2 = (nt << 4) + lc;
      int p  = c2 * 40 + ((quad ^ ((c2 >> 3) & 3)) << 3);
      short8 bfrag = *(const short8*)(Blds + p);
      acc[nt] = MFMA16(av, bfrag, acc[nt]);
    }
    __syncthreads();
  }
  #pragma unroll
  for (int nt = 0; nt < 4; ++nt){
    #pragma unroll
    for (int i = 0; i < 4; ++i){
      int m = bm + wid * 16 + quad * 4 + i;
      int n = bn + (nt << 4) + lc;
      float v = acc[nt][i] + bias[n];
      if (F32OUT) ((float*)Cv)[(size_t)m * N + n] = v;
      else        ((ushort*)Cv)[(size_t)m * N + n] = f2bf(v);
    }
  }
}

// ---------------------------------------------------------------------------
// Fused 3-layer pipelined GRU recurrence. 96 WGs x 384 threads.
// role = bid/32 (layer), g = bid%32 (owns units [16g,16g+16)).
// Global step s: layer L computes t = s - L. One 96-flag lockstep/step.
// Rings (depth 4, sc0/sc1 exchange): h0/h1/h2 carry, out0, pred0, xw1.
// L1 publishes xw1 = out0@Ks (no bias); L2 uses xw2 = xw1 + a0*(pred0@Ks).
// L2 writes comb = out0 + a1*pred0 + a2*pred1 straight to HBM.
// ---------------------------------------------------------------------------
#define NWG 96
#define SMAX 1026

__global__ __launch_bounds__(384, 2) void rec3_k(
    const ushort* __restrict__ xw0,   // [32*1024,1536] bf16, row = b*1024+t
    const ushort* __restrict__ R0b,   // [512,1536]
    const ushort* __restrict__ Ksb,   // [512,1536]
    const ushort* __restrict__ Rsb,   // [512,1536]
    const float*  __restrict__ b0v,   // [2,1536]
    const float*  __restrict__ bsv,   // [2,1536]
    const float*  __restrict__ h00,
    const float*  __restrict__ h01,
    const float*  __restrict__ h02,
    const float*  __restrict__ av,    // [3]
    ushort* __restrict__ comb,        // [32*1024,512] bf16
    ushort* __restrict__ rings,
    int* __restrict__ flags)          // [SMAX][96]
{
  __shared__ float m_lds[3][32][17];
  __shared__ float x_lds[3][32][17];
  __shared__ float bias_l[96];                       // [0:48) b_rec, [48:96) b_in(bs)
  __shared__ __align__(16) ushort ks_lds[3 * 16 * 64 * 8];  // 48 KB

  const int tid  = threadIdx.x;
  const int wid  = tid >> 6;
  const int lane = tid & 63;
  const int quad = lane >> 4;
  const int lc   = lane & 15;
  const int bid  = blockIdx.x;
  const int role = bid >> 5;
  const int g    = bid & 31;
  const int ug0  = g << 4;
  const int gate = wid % 3, mtile = wid / 3;
  const int col0 = (gate << 9) + ug0;

  ushort* h_ring    = rings + role * 65536;   // h0 / h1 / h2 carry rings
  ushort* out0ring  = rings + 196608;
  ushort* pred0ring = rings + 262144;
  ushort* xw1ring   = rings + 327680;         // [4][32][1536]

  // ---- recurrent-weight fragments in VGPRs ----
  const ushort* Rw = (role == 0) ? R0b : Rsb;
  short8 bfragR[16];
  #pragma unroll
  for (int f = 0; f < 16; ++f){
    short8 v;
    #pragma unroll
    for (int j = 0; j < 8; ++j)
      v[j] = (short)Rw[(size_t)(f * 32 + quad * 8 + j) * 1536 + col0 + lc];
    bfragR[f] = v;
  }
  // ---- Ks slice into LDS (roles 1,2), one wave per gate ----
  if (role > 0 && mtile == 0){
    #pragma unroll
    for (int f = 0; f < 16; ++f){
      short8 v;
      #pragma unroll
      for (int j = 0; j < 8; ++j)
        v[j] = (short)Ksb[(size_t)(f * 32 + quad * 8 + j) * 1536 + col0 + lc];
      *(short8*)(ks_lds + (((gate << 4) + f) << 9) + (lane << 3)) = v;
    }
  }
  const float* brec = ((role == 0) ? b0v : bsv) + 1536;
  if (tid < 48) bias_l[tid] = brec[(tid >> 4) * 512 + ug0 + (tid & 15)];
  if (tid >= 48 && tid < 96) bias_l[tid] = bsv[((tid - 48) >> 4) * 512 + ug0 + ((tid - 48) & 15)];
  const float a0 = av[0], a1 = av[1], a2 = av[2];
  const float* hinit = (role == 0) ? h00 : (role == 1) ? h01 : h02;

  const int  b0i  = tid >> 4;
  const int  u0   = tid & 15;
  const int  b1i  = (tid + 384) >> 4;
  const bool has1 = (tid < 128);
  const int  uu   = ug0 + u0;
  float hp0 = hinit[uu];
  float hp1 = hp0;

  // ---- role0 xw prefetch for t=0 ----
  ushort xz0 = 0, xr0 = 0, xh0 = 0, xz1 = 0, xr1 = 0, xh1 = 0;
  if (role == 0){
    size_t r0_ = ((size_t)b0i * 1024) * 1536 + uu;
    xz0 = xw0[r0_]; xr0 = xw0[r0_ + 512]; xh0 = xw0[r0_ + 1024];
    if (has1){
      size_t r1_ = ((size_t)b1i * 1024) * 1536 + uu;
      xz1 = xw0[r1_]; xr1 = xw0[r1_ + 512]; xh1 = xw0[r1_ + 1024];
    }
  }
  __syncthreads();

  long budget = 20000000L;  // spin safety valve: degrade, don't hang
  for (int s = 0; s < SMAX; ++s){
    const int  t      = s - role;
    const bool active = (t >= 0) && (t < 1024);
    const int  slot   = t & 3;
    const int  pslot  = (t - 1) & 3;

    // role0: prefetch next xw (independent of flags)
    ushort nz0 = 0, nr0 = 0, nh0 = 0, nz1 = 0, nr1 = 0, nh1 = 0;
    if (role == 0 && t >= 0 && t < 1023){
      size_t r0_ = ((size_t)b0i * 1024 + t + 1) * 1536 + uu;
      nz0 = xw0[r0_]; nr0 = xw0[r0_ + 512]; nh0 = xw0[r0_ + 1024];
      if (has1){
        size_t r1_ = ((size_t)b1i * 1024 + t + 1) * 1536 + uu;
        nz1 = xw0[r1_]; nr1 = xw0[r1_ + 512]; nh1 = xw0[r1_ + 1024];
      }
    }

    if (s > 0){
      if (wid == 0){
        const int* fb = flags + (size_t)(s - 1) * NWG;
        while (budget > 0){
          int v1 = __hip_atomic_load(fb + lane, __ATOMIC_RELAXED, __HIP_MEMORY_SCOPE_AGENT);
          int v2 = (lane < 32)
                   ? __hip_atomic_load(fb + 64 + lane, __ATOMIC_RELAXED, __HIP_MEMORY_SCOPE_AGENT)
                   : 1;
          if (__ballot((v1 != 0) && (v2 != 0)) == ~0ull) break;
          --budget;
        }
      }
      __syncthreads();
    }

    // role2: early scalar ring loads (used in gates + comb)
    float o_s0 = 0, p_s0 = 0, x1z0 = 0, x1r0 = 0, x1h0 = 0;
    float o_s1 = 0, p_s1 = 0, x1z1 = 0, x1r1 = 0, x1h1 = 0;
    if (role == 2 && active){
      int rb0 = slot * 16384 + b0i * 512 + uu;
      int xb0 = slot * 49152 + b0i * 1536 + uu;
      o_s0 = ld_ring_bf(out0ring, rb0);
      p_s0 = ld_ring_bf(pred0ring, rb0);
      x1z0 = ld_ring_bf(xw1ring, xb0);
      x1r0 = ld_ring_bf(xw1ring, xb0 + 512);
      x1h0 = ld_ring_bf(xw1ring, xb0 + 1024);
      if (has1){
        int rb1 = slot * 16384 + b1i * 512 + uu;
        int xb1 = slot * 49152 + b1i * 1536 + uu;
        o_s1 = ld_ring_bf(out0ring, rb1);
        p_s1 = ld_ring_bf(pred0ring, rb1);
        x1z1 = ld_ring_bf(xw1ring, xb1);
        x1r1 = ld_ring_bf(xw1ring, xb1 + 512);
        x1h1 = ld_ring_bf(xw1ring, xb1 + 1024);
      }
    }

    if (active){
      // ---- A-frags for recurrent matmul ----
      short8 avm[16];
      if (t == 0){
        #pragma unroll
        for (int f = 0; f < 16; ++f){
          short8 v;
          #pragma unroll
          for (int j = 0; j < 8; ++j)
            v[j] = (short)f2bf(hinit[f * 32 + quad * 8 + j]);
          avm[f] = v;
        }
      } else {
        const ushort* hr = h_ring + pslot * 16384 + (mtile * 16 + lc) * 512 + quad * 8;
        #pragma unroll
        for (int f = 0; f < 16; ++f) avm[f] = ld_hc16(hr + f * 32);
      }

      f32x4 am0 = {0,0,0,0}, am1 = {0,0,0,0};
      if (role == 0){
        #pragma unroll
        for (int f = 0; f < 16; ++f){
          if (f & 1) am1 = MFMA16(avm[f], bfragR[f], am1);
          else       am0 = MFMA16(avm[f], bfragR[f], am0);
        }
        f32x4 am = am0 + am1;
        #pragma unroll
        for (int i = 0; i < 4; ++i)
          m_lds[gate][(mtile << 4) + (quad << 2) + i][lc] = am[i];
      } else {
        const ushort* xr_ = ((role == 1) ? out0ring : pred0ring)
                          + slot * 16384 + (mtile * 16 + lc) * 512 + quad * 8;
        short8 avx[16];
        #pragma unroll
        for (int f = 0; f < 16; ++f) avx[f] = ld_hc16(xr_ + f * 32);
        f32x4 ax0 = {0,0,0,0}, ax1 = {0,0,0,0};
        #pragma unroll
        for (int f = 0; f < 16; ++f){
          short8 bx = *(const short8*)(ks_lds + (((gate << 4) + f) << 9) + (lane << 3));
          if (f & 1){ am1 = MFMA16(avm[f], bfragR[f], am1); ax1 = MFMA16(avx[f], bx, ax1); }
          else      { am0 = MFMA16(avm[f], bfragR[f], am0); ax0 = MFMA16(avx[f], bx, ax0); }
        }
        f32x4 am = am0 + am1, ax = ax0 + ax1;
        #pragma unroll
        for (int i = 0; i < 4; ++i){
          m_lds[gate][(mtile << 4) + (quad << 2) + i][lc] = am[i];
          x_lds[gate][(mtile << 4) + (quad << 2) + i][lc] = ax[i];
        }
      }
    }
    __syncthreads();

    if (active){
      // ---- item 0 ----
      {
        int b = b0i;
        float mz = m_lds[0][b][u0] + bias_l[u0];
        float mr = m_lds[1][b][u0] + bias_l[16 + u0];
        float mh = m_lds[2][b][u0] + bias_l[32 + u0];
        float xz, xr, xh;
        if (role == 0){ xz = bf2f(xz0); xr = bf2f(xr0); xh = bf2f(xh0); }
        else if (role == 1){
          xz = x_lds[0][b][u0] + bias_l[48 + u0];
          xr = x_lds[1][b][u0] + bias_l[64 + u0];
          xh = x_lds[2][b][u0] + bias_l[80 + u0];
        } else {
          xz = x1z0 + a0 * x_lds[0][b][u0] + bias_l[48 + u0];
          xr = x1r0 + a0 * x_lds[1][b][u0] + bias_l[64 + u0];
          xh = x1h0 + a0 * x_lds[2][b][u0] + bias_l[80 + u0];
        }
        float z  = 1.f / (1.f + __expf(-(xz + mz)));
        float r  = 1.f / (1.f + __expf(-(xr + mr)));
        float axv = xh + r * mh;
        float hh = 1.f - 2.f / (1.f + __expf(2.f * axv));
        float hn = z * hp0 + (1.f - z) * hh;
        float hcv = hn + 0.1f * (hp0 - hn);
        hp0 = hcv;
        int rb = slot * 16384 + b * 512 + uu;
        st_hc2(h_ring + rb, f2bf(hcv));
        if (role == 0) st_hc2(out0ring + rb, f2bf(hn));
        else if (role == 1){
          st_hc2(pred0ring + rb, f2bf(hn));
          int xb = slot * 49152 + b * 1536 + uu;
          st_hc2(xw1ring + xb,        f2bf(x_lds[0][b][u0]));
          st_hc2(xw1ring + xb + 512,  f2bf(x_lds[1][b][u0]));
          st_hc2(xw1ring + xb + 1024, f2bf(x_lds[2][b][u0]));
        } else {
          comb[((size_t)b * 1024 + t) * 512 + uu] = f2bf(o_s0 + a1 * p_s0 + a2 * hn);
        }
      }
      // ---- item 1 ----
      if (has1){
        int b = b1i;
        float mz = m_lds[0][b][u0] + bias_l[u0];
        float mr = m_lds[1][b][u0] + bias_l[16 + u0];
        float mh = m_lds[2][b][u0] + bias_l[32 + u0];
        float xz, xr, xh;
        if (role == 0){ xz = bf2f(xz1); xr = bf2f(xr1); xh = bf2f(xh1); }
        else if (role == 1){
          xz = x_lds[0][b][u0] + bias_l[48 + u0];
          xr = x_lds[1][b][u0] + bias_l[64 + u0];
          xh = x_lds[2][b][u0] + bias_l[80 + u0];
        } else {
          xz = x1z1 + a0 * x_lds[0][b][u0] + bias_l[48 + u0];
          xr = x1r1 + a0 * x_lds[1][b][u0] + bias_l[64 + u0];
          xh = x1h1 + a0 * x_lds[2][b][u0] + bias_l[80 + u0];
        }
        float z  = 1.f / (1.f + __expf(-(xz + mz)));
        float r  = 1.f / (1.f + __expf(-(xr + mr)));
        float axv = xh + r * mh;
        float hh = 1.f - 2.f / (1.f + __expf(2.f * axv));
        float hn = z * hp1 + (1.f - z) * hh;
        float hcv = hn + 0.1f * (hp1 - hn);
        hp1 = hcv;
        int rb = slot * 16384 + b * 512 + uu;
        st_hc2(h_ring + rb, f2bf(hcv));
        if (role == 0) st_hc2(out0ring + rb, f2bf(hn));
        else if (role == 1){
          st_hc2(pred0ring + rb, f2bf(hn));
          int xb = slot * 49152 + b * 1536 + uu;
          st_hc2(xw1ring + xb,        f2bf(x_lds[0][b][u0]));
          st_hc2(xw1ring + xb + 512,  f2bf(x_lds[1][b][u0]));
          st_hc2(xw1ring + xb + 1024, f2bf(x_lds[2][b][u0]));
        } else {
          comb[((size_t)b * 1024 + t) * 512 + uu] = f2bf(o_s1 + a1 * p_s1 + a2 * hn);
        }
      }
    }
    asm volatile("s_waitcnt vmcnt(0)" ::: "memory");  // drain ring stores
    __syncthreads();
    if (tid == 0)
      __hip_atomic_store(flags + (size_t)s * NWG + bid, 1,
                         __ATOMIC_RELAXED, __HIP_MEMORY_SCOPE_AGENT);

    if (role == 0){
      xz0 = nz0; xr0 = nr0; xh0 = nh0;
      xz1 = nz1; xr1 = nr1; xh1 = nh1;
    }
  }
}

// ---------------------------------------------------------------------------
extern "C" void kernel_launch(void* const* d_in, const int* in_sizes, int n_in,
                              void* d_out, int out_size, void* d_ws, size_t ws_size,
                              hipStream_t stream)
{
  const float* x   = (const float*)d_in[0];
  const float* k0  = (const float*)d_in[1];
  const float* r0  = (const float*)d_in[2];
  const float* b0  = (const float*)d_in[3];
  const float* ks  = (const float*)d_in[4];
  const float* rs  = (const float*)d_in[5];
  const float* bs  = (const float*)d_in[6];
  const float* h00 = (const float*)d_in[7];
  const float* h01 = (const float*)d_in[8];
  const float* h02 = (const float*)d_in[9];
  const float* a   = (const float*)d_in[10];
  const float* wd  = (const float*)d_in[11];
  const float* bd  = (const float*)d_in[12];
  float* outp = (float*)d_out;

  // ws layout (bytes), ~141.4 MB total:
  //   [0,        100663296)  XW0   [32768,1536] bf16
  //   [100663296,134217728)  comb  [32768,512] bf16 (first 16.8MB aliases x_bf)
  //   [134217728,135266304)  rings (1 MB)
  //   [135266304,135660288)  flags [1026][96] int
  //   [135660288,...]        bf16 weights k0b,r0b,ksb,rsb,wdb
  char* ws = (char*)d_ws;
  ushort* XW    = (ushort*)(ws);
  ushort* combp = (ushort*)(ws + 100663296u);
  ushort* xbf   = combp;                      // alias: dead before rec3_k runs
  ushort* rings = (ushort*)(ws + 134217728u);
  int*    flags = (int*)   (ws + 135266304u);
  ushort* k0b   = (ushort*)(ws + 135660288u);
  ushort* r0b   = (ushort*)(ws + 136446720u);
  ushort* ksb   = (ushort*)(ws + 138019584u);
  ushort* rsb   = (ushort*)(ws + 139592448u);
  ushort* wdb   = (ushort*)(ws + 141165312u);

  hipMemsetAsync(flags, 0, SMAX * NWG * sizeof(int), stream);

  dim3 blk(256);
  cvt_k<<<dim3(8192), blk, 0, stream>>>(x,  xbf, 8388608);
  cvt_k<<<dim3(384),  blk, 0, stream>>>(k0, k0b, 393216);
  cvt_k<<<dim3(768),  blk, 0, stream>>>(r0, r0b, 786432);
  cvt_k<<<dim3(768),  blk, 0, stream>>>(ks, ksb, 786432);
  cvt_k<<<dim3(768),  blk, 0, stream>>>(rs, rsb, 786432);
  cvt_k<<<dim3(128),  blk, 0, stream>>>(wd, wdb, 131072);

  // Layer-0 input projection (bulk GEMM)
  gemm_bias_k<0><<<dim3(512 * 24), blk, 0, stream>>>(xbf, k0b, b0, XW, 32768, 1536, 256);
  // Fused pipelined 3-layer recurrence
  rec3_k<<<dim3(NWG), dim3(384), 0, stream>>>(XW, r0b, ksb, rsb, b0, bs,
                                              h00, h01, h02, a, combp, rings, flags);
  // Final projection: comb @ wd + bd -> fp32 d_out
  gemm_bias_k<1><<<dim3(512 * 4), blk, 0, stream>>>(combp, wdb, bd, outp, 32768, 256, 512);
}

// Round 5
// 14849.933 us; speedup vs baseline: 1.6287x; 1.0101x over previous
//
#include <hip/hip_runtime.h>

typedef __attribute__((ext_vector_type(8))) short short8;
typedef __attribute__((ext_vector_type(4))) float f32x4;
typedef __attribute__((ext_vector_type(4))) unsigned short u16x4;
typedef unsigned short ushort;
typedef unsigned long long ull;

#define MFMA16(a,b,c) __builtin_amdgcn_mfma_f32_16x16x32_bf16((a),(b),(c),0,0,0)

static __device__ __forceinline__ float bf2f(ushort u){
  union { unsigned int i; float f; } z; z.i = ((unsigned int)u) << 16; return z.f;
}
static __device__ __forceinline__ ushort f2bf(float f){
  union { float f; unsigned int i; } z; z.f = f;
  unsigned int x = z.i;
  unsigned int r = (x + 0x7fffu + ((x >> 16) & 1u)) >> 16;   // RNE
  return (ushort)r;
}

// 16B coherence-point load (2x u64 agent atomics, bypass stale L1/L2)
static __device__ __forceinline__ short8 ld_hc16(const ushort* p){
  union { ull q[2]; short8 v; } u;
  u.q[0] = __hip_atomic_load((const ull*)p, __ATOMIC_RELAXED, __HIP_MEMORY_SCOPE_AGENT);
  u.q[1] = __hip_atomic_load((const ull*)(p + 4), __ATOMIC_RELAXED, __HIP_MEMORY_SCOPE_AGENT);
  return u.v;
}
// single bf16 from ring via aligned u32 agent atomic
static __device__ __forceinline__ float ld_ring_bf(const ushort* base, int idx){
  const unsigned int* p = (const unsigned int*)(base + (idx & ~1));
  unsigned int w = __hip_atomic_load(p, __ATOMIC_RELAXED, __HIP_MEMORY_SCOPE_AGENT);
  return bf2f((idx & 1) ? (ushort)(w >> 16) : (ushort)(w & 0xffffu));
}
// 2B / 8B write-through stores to coherence point
static __device__ __forceinline__ void st_hc2(ushort* p, ushort v){
  unsigned int vv = v;
  asm volatile("global_store_short %0, %1, off sc0 sc1" :: "v"(p), "v"(vv) : "memory");
}
static __device__ __forceinline__ void st_hc8(ushort* p, ull v){
  asm volatile("global_store_dwordx2 %0, %1, off sc0 sc1" :: "v"(p), "v"(v) : "memory");
}

// ---------------------------------------------------------------------------
// fp32 -> bf16 convert, 4 elems/thread
// ---------------------------------------------------------------------------
__global__ __launch_bounds__(256) void cvt_k(
    const float* __restrict__ in, ushort* __restrict__ out, int n)
{
  int i = (blockIdx.x * 256 + threadIdx.x) * 4;
  if (i < n){
    float4 v = *(const float4*)(in + i);
    u16x4 o = { f2bf(v.x), f2bf(v.y), f2bf(v.z), f2bf(v.w) };
    *(u16x4*)(out + i) = o;
  }
}

// ---------------------------------------------------------------------------
// GEMM: C[M,N] = A[M,K](bf16) @ B[K,N](bf16) + bias[N](fp32).
// ---------------------------------------------------------------------------
template<int F32OUT>
__global__ __launch_bounds__(256) void gemm_bias_k(
    const ushort* __restrict__ A,
    const ushort* __restrict__ B,
    const float*  __restrict__ bias,
    void* __restrict__ Cv,
    int M, int N, int K)
{
  __shared__ __align__(16) ushort Blds[64 * 40];
  const int tid  = threadIdx.x;
  const int wid  = tid >> 6;
  const int lane = tid & 63;
  const int quad = lane >> 4;
  const int lc   = lane & 15;
  const int nb   = N >> 6;
  const int bn   = (blockIdx.x % nb) << 6;
  const int bm   = (blockIdx.x / nb) << 6;

  const int sk  = tid >> 3;
  const int scg = tid & 7;

  f32x4 acc[4] = {{0,0,0,0},{0,0,0,0},{0,0,0,0},{0,0,0,0}};
  const int arow = bm + wid * 16 + lc;
  const ushort* aptr = A + (size_t)arow * K + quad * 8;

  for (int k0 = 0; k0 < K; k0 += 32){
    short8 bv = *(const short8*)(B + (size_t)(k0 + sk) * N + bn + (scg << 3));
    #pragma unroll
    for (int i = 0; i < 8; ++i){
      int c = (scg << 3) + i;
      int p = c * 40 + (((sk >> 3) ^ (scg & 3)) << 3) + (sk & 7);
      Blds[p] = (ushort)bv[i];
    }
    __syncthreads();
    short8 av = *(const short8*)(aptr + k0);
    #pragma unroll
    for (int nt = 0; nt < 4; ++nt){
      int c2 = (nt << 4) + lc;
      int p  = c2 * 40 + ((quad ^ ((c2 >> 3) & 3)) << 3);
      short8 bfrag = *(const short8*)(Blds + p);
      acc[nt] = MFMA16(av, bfrag, acc[nt]);
    }
    __syncthreads();
  }
  #pragma unroll
  for (int nt = 0; nt < 4; ++nt){
    #pragma unroll
    for (int i = 0; i < 4; ++i){
      int m = bm + wid * 16 + quad * 4 + i;
      int n = bn + (nt << 4) + lc;
      float v = acc[nt][i] + bias[n];
      if (F32OUT) ((float*)Cv)[(size_t)m * N + n] = v;
      else        ((ushort*)Cv)[(size_t)m * N + n] = f2bf(v);
    }
  }
}

// ---------------------------------------------------------------------------
// Fused 3-layer pipelined GRU recurrence, DE-LOCKSTEPPED. 96 WGs x 384 thr.
// role = bid/32 (layer), g = bid%32 (units [16g,16g+16)). Role r computes
// t at global step s = t + r. Per-role flag planes flags[r][s][32]:
//   role r waits: own[s-1] (h ring), prev-role[s-1] (stream ring),
//   and (roles 0,1) role2[s-6] (ring-depth-8 back-pressure).
// Rings depth 8 via sc0/sc1 coherence-point exchange. Publish-early:
// flag fires right after ring stores drain; role2's comb HBM stores follow.
// ---------------------------------------------------------------------------
#define NWG 96
#define RD 8
#define FSTEPS 1032

__global__ __launch_bounds__(384, 2) void rec3_k(
    const ushort* __restrict__ xw0,   // [32*1024,1536] bf16, row = b*1024+t
    const ushort* __restrict__ R0b,   // [512,1536]
    const ushort* __restrict__ Ksb,   // [512,1536]
    const ushort* __restrict__ Rsb,   // [512,1536]
    const float*  __restrict__ b0v,   // [2,1536]
    const float*  __restrict__ bsv,   // [2,1536]
    const float*  __restrict__ h00,
    const float*  __restrict__ h01,
    const float*  __restrict__ h02,
    const float*  __restrict__ av,    // [3]
    ushort* __restrict__ comb,        // [32*1024,512] bf16
    ushort* __restrict__ rings,
    int* __restrict__ flags)          // [3][FSTEPS][32]
{
  __shared__ float m_lds[3][32][17];
  __shared__ float x_lds[3][32][17];
  __shared__ float bias_l[96];                       // [0:48) b_rec, [48:96) b_in(bs)
  __shared__ __align__(16) ushort ks_lds[3 * 16 * 64 * 8];  // 48 KB

  const int tid  = threadIdx.x;
  const int wid  = tid >> 6;
  const int lane = tid & 63;
  const int quad = lane >> 4;
  const int lc   = lane & 15;
  const int bid  = blockIdx.x;
  const int role = bid >> 5;
  const int g    = bid & 31;
  const int ug0  = g << 4;
  const int gate = wid % 3, mtile = wid / 3;
  const int col0 = (gate << 9) + ug0;

  // ring layout (ushort units): h[3] 131072 each; out0 131072; pred0 131072;
  // xw1 [8][32][512][4] = 524288
  ushort* h_ring    = rings + role * 131072;
  ushort* out0ring  = rings + 393216;
  ushort* pred0ring = rings + 524288;
  ushort* xw1ring   = rings + 655360;

  // ---- recurrent-weight fragments in VGPRs ----
  const ushort* Rw = (role == 0) ? R0b : Rsb;
  short8 bfragR[16];
  #pragma unroll
  for (int f = 0; f < 16; ++f){
    short8 v;
    #pragma unroll
    for (int j = 0; j < 8; ++j)
      v[j] = (short)Rw[(size_t)(f * 32 + quad * 8 + j) * 1536 + col0 + lc];
    bfragR[f] = v;
  }
  // ---- Ks slice into LDS (roles 1,2), one wave per gate ----
  if (role > 0 && mtile == 0){
    #pragma unroll
    for (int f = 0; f < 16; ++f){
      short8 v;
      #pragma unroll
      for (int j = 0; j < 8; ++j)
        v[j] = (short)Ksb[(size_t)(f * 32 + quad * 8 + j) * 1536 + col0 + lc];
      *(short8*)(ks_lds + (((gate << 4) + f) << 9) + (lane << 3)) = v;
    }
  }
  const float* brec = ((role == 0) ? b0v : bsv) + 1536;
  if (tid < 48) bias_l[tid] = brec[(tid >> 4) * 512 + ug0 + (tid & 15)];
  if (tid >= 48 && tid < 96) bias_l[tid] = bsv[((tid - 48) >> 4) * 512 + ug0 + ((tid - 48) & 15)];
  const float a0 = av[0], a1 = av[1], a2 = av[2];
  const float* hinit = (role == 0) ? h00 : (role == 1) ? h01 : h02;

  const int  b0i  = tid >> 4;
  const int  u0   = tid & 15;
  const int  b1i  = (tid + 384) >> 4;
  const bool has1 = (tid < 128);
  const int  uu   = ug0 + u0;
  float hp0 = hinit[uu];
  float hp1 = hp0;

  // ---- role0 xw prefetch for t=0 ----
  ushort xz0 = 0, xr0 = 0, xh0 = 0, xz1 = 0, xr1 = 0, xh1 = 0;
  if (role == 0){
    size_t r0_ = ((size_t)b0i * 1024) * 1536 + uu;
    xz0 = xw0[r0_]; xr0 = xw0[r0_ + 512]; xh0 = xw0[r0_ + 1024];
    if (has1){
      size_t r1_ = ((size_t)b1i * 1024) * 1536 + uu;
      xz1 = xw0[r1_]; xr1 = xw0[r1_ + 512]; xh1 = xw0[r1_ + 1024];
    }
  }
  __syncthreads();

  long budget = 40000000L;  // spin safety valve: degrade, don't hang
  for (int t = 0; t < 1024; ++t){
    const int s     = t + role;
    const int slot  = t & (RD - 1);
    const int pslot = (t - 1) & (RD - 1);

    // role0: prefetch next xw (independent of flags)
    ushort nz0 = 0, nr0 = 0, nh0 = 0, nz1 = 0, nr1 = 0, nh1 = 0;
    if (role == 0 && t < 1023){
      size_t r0_ = ((size_t)b0i * 1024 + t + 1) * 1536 + uu;
      nz0 = xw0[r0_]; nr0 = xw0[r0_ + 512]; nh0 = xw0[r0_ + 1024];
      if (has1){
        size_t r1_ = ((size_t)b1i * 1024 + t + 1) * 1536 + uu;
        nz1 = xw0[r1_]; nr1 = xw0[r1_ + 512]; nh1 = xw0[r1_ + 1024];
      }
    }

    // ---- de-lockstepped wait ----
    {
      const bool needO = (t > 0);                       // own h ring
      const bool needP = (role >= 1);                   // prev-role stream
      const bool needF = (role <= 1) && (s >= RD);      // ring back-pressure
      if ((needO || needP || needF) && wid == 0){
        const int  l    = lane & 31;
        const int* fo   = flags + (role * FSTEPS + (s - 1)) * 32 + l;
        const int* fp   = flags + ((role - 1) * FSTEPS + (s - 1)) * 32 + l;
        const int* ff   = flags + (2 * FSTEPS + (s - 6)) * 32 + l;
        while (budget > 0){
          bool ok = true;
          if (needO) ok &= (__hip_atomic_load(fo, __ATOMIC_RELAXED, __HIP_MEMORY_SCOPE_AGENT) != 0);
          if (needP) ok &= (__hip_atomic_load(fp, __ATOMIC_RELAXED, __HIP_MEMORY_SCOPE_AGENT) != 0);
          if (needF) ok &= (__hip_atomic_load(ff, __ATOMIC_RELAXED, __HIP_MEMORY_SCOPE_AGENT) != 0);
          if (__ballot(ok) == ~0ull) break;
          --budget;
        }
      }
      __syncthreads();
    }

    // role2: scalar ring loads for gates + comb (in flight with A-frag loads)
    float o_s0 = 0, p_s0 = 0, x1z0 = 0, x1r0 = 0, x1h0 = 0;
    float o_s1 = 0, p_s1 = 0, x1z1 = 0, x1r1 = 0, x1h1 = 0;
    if (role == 2){
      int rb0 = slot * 16384 + b0i * 512 + uu;
      o_s0 = ld_ring_bf(out0ring, rb0);
      p_s0 = ld_ring_bf(pred0ring, rb0);
      ull xwp = __hip_atomic_load((const ull*)(xw1ring + (size_t)((slot * 32 + b0i) * 512 + uu) * 4),
                                  __ATOMIC_RELAXED, __HIP_MEMORY_SCOPE_AGENT);
      x1z0 = bf2f((ushort)(xwp & 0xffffu));
      x1r0 = bf2f((ushort)((xwp >> 16) & 0xffffu));
      x1h0 = bf2f((ushort)((xwp >> 32) & 0xffffu));
      if (has1){
        int rb1 = slot * 16384 + b1i * 512 + uu;
        o_s1 = ld_ring_bf(out0ring, rb1);
        p_s1 = ld_ring_bf(pred0ring, rb1);
        ull xwq = __hip_atomic_load((const ull*)(xw1ring + (size_t)((slot * 32 + b1i) * 512 + uu) * 4),
                                    __ATOMIC_RELAXED, __HIP_MEMORY_SCOPE_AGENT);
        x1z1 = bf2f((ushort)(xwq & 0xffffu));
        x1r1 = bf2f((ushort)((xwq >> 16) & 0xffffu));
        x1h1 = bf2f((ushort)((xwq >> 32) & 0xffffu));
      }
    }

    // ---- A-frags + recurrent (and input) MFMA ----
    {
      short8 avm[16];
      if (t == 0){
        #pragma unroll
        for (int f = 0; f < 16; ++f){
          short8 v;
          #pragma unroll
          for (int j = 0; j < 8; ++j)
            v[j] = (short)f2bf(hinit[f * 32 + quad * 8 + j]);
          avm[f] = v;
        }
      } else {
        const ushort* hr = h_ring + pslot * 16384 + (mtile * 16 + lc) * 512 + quad * 8;
        #pragma unroll
        for (int f = 0; f < 16; ++f) avm[f] = ld_hc16(hr + f * 32);
      }

      f32x4 am0 = {0,0,0,0}, am1 = {0,0,0,0};
      if (role == 0){
        #pragma unroll
        for (int f = 0; f < 16; ++f){
          if (f & 1) am1 = MFMA16(avm[f], bfragR[f], am1);
          else       am0 = MFMA16(avm[f], bfragR[f], am0);
        }
        f32x4 am = am0 + am1;
        #pragma unroll
        for (int i = 0; i < 4; ++i)
          m_lds[gate][(mtile << 4) + (quad << 2) + i][lc] = am[i];
      } else {
        const ushort* xr_ = ((role == 1) ? out0ring : pred0ring)
                          + slot * 16384 + (mtile * 16 + lc) * 512 + quad * 8;
        short8 avx[16];
        #pragma unroll
        for (int f = 0; f < 16; ++f) avx[f] = ld_hc16(xr_ + f * 32);
        f32x4 ax0 = {0,0,0,0}, ax1 = {0,0,0,0};
        #pragma unroll
        for (int f = 0; f < 16; ++f){
          short8 bx = *(const short8*)(ks_lds + (((gate << 4) + f) << 9) + (lane << 3));
          if (f & 1){ am1 = MFMA16(avm[f], bfragR[f], am1); ax1 = MFMA16(avx[f], bx, ax1); }
          else      { am0 = MFMA16(avm[f], bfragR[f], am0); ax0 = MFMA16(avx[f], bx, ax0); }
        }
        f32x4 am = am0 + am1, ax = ax0 + ax1;
        #pragma unroll
        for (int i = 0; i < 4; ++i){
          m_lds[gate][(mtile << 4) + (quad << 2) + i][lc] = am[i];
          x_lds[gate][(mtile << 4) + (quad << 2) + i][lc] = ax[i];
        }
      }
    }
    __syncthreads();

    // ---- gate math; ring stores only (publish-early) ----
    ushort cb0 = 0, cb1 = 0;
    {
      int b = b0i;
      float mz = m_lds[0][b][u0] + bias_l[u0];
      float mr = m_lds[1][b][u0] + bias_l[16 + u0];
      float mh = m_lds[2][b][u0] + bias_l[32 + u0];
      float xz, xr, xh;
      if (role == 0){ xz = bf2f(xz0); xr = bf2f(xr0); xh = bf2f(xh0); }
      else if (role == 1){
        xz = x_lds[0][b][u0] + bias_l[48 + u0];
        xr = x_lds[1][b][u0] + bias_l[64 + u0];
        xh = x_lds[2][b][u0] + bias_l[80 + u0];
      } else {
        xz = x1z0 + a0 * x_lds[0][b][u0] + bias_l[48 + u0];
        xr = x1r0 + a0 * x_lds[1][b][u0] + bias_l[64 + u0];
        xh = x1h0 + a0 * x_lds[2][b][u0] + bias_l[80 + u0];
      }
      float z  = 1.f / (1.f + __expf(-(xz + mz)));
      float r  = 1.f / (1.f + __expf(-(xr + mr)));
      float axv = xh + r * mh;
      float hh = 1.f - 2.f / (1.f + __expf(2.f * axv));
      float hn = z * hp0 + (1.f - z) * hh;
      float hcv = hn + 0.1f * (hp0 - hn);
      hp0 = hcv;
      int rb = slot * 16384 + b * 512 + uu;
      st_hc2(h_ring + rb, f2bf(hcv));
      if (role == 0) st_hc2(out0ring + rb, f2bf(hn));
      else if (role == 1){
        st_hc2(pred0ring + rb, f2bf(hn));
        ull pv = (ull)f2bf(x_lds[0][b][u0])
               | ((ull)f2bf(x_lds[1][b][u0]) << 16)
               | ((ull)f2bf(x_lds[2][b][u0]) << 32);
        st_hc8(xw1ring + (size_t)((slot * 32 + b) * 512 + uu) * 4, pv);
      } else {
        cb0 = f2bf(o_s0 + a1 * p_s0 + a2 * hn);
      }
    }
    if (has1){
      int b = b1i;
      float mz = m_lds[0][b][u0] + bias_l[u0];
      float mr = m_lds[1][b][u0] + bias_l[16 + u0];
      float mh = m_lds[2][b][u0] + bias_l[32 + u0];
      float xz, xr, xh;
      if (role == 0){ xz = bf2f(xz1); xr = bf2f(xr1); xh = bf2f(xh1); }
      else if (role == 1){
        xz = x_lds[0][b][u0] + bias_l[48 + u0];
        xr = x_lds[1][b][u0] + bias_l[64 + u0];
        xh = x_lds[2][b][u0] + bias_l[80 + u0];
      } else {
        xz = x1z1 + a0 * x_lds[0][b][u0] + bias_l[48 + u0];
        xr = x1r1 + a0 * x_lds[1][b][u0] + bias_l[64 + u0];
        xh = x1h1 + a0 * x_lds[2][b][u0] + bias_l[80 + u0];
      }
      float z  = 1.f / (1.f + __expf(-(xz + mz)));
      float r  = 1.f / (1.f + __expf(-(xr + mr)));
      float axv = xh + r * mh;
      float hh = 1.f - 2.f / (1.f + __expf(2.f * axv));
      float hn = z * hp1 + (1.f - z) * hh;
      float hcv = hn + 0.1f * (hp1 - hn);
      hp1 = hcv;
      int rb = slot * 16384 + b * 512 + uu;
      st_hc2(h_ring + rb, f2bf(hcv));
      if (role == 0) st_hc2(out0ring + rb, f2bf(hn));
      else if (role == 1){
        st_hc2(pred0ring + rb, f2bf(hn));
        ull pv = (ull)f2bf(x_lds[0][b][u0])
               | ((ull)f2bf(x_lds[1][b][u0]) << 16)
               | ((ull)f2bf(x_lds[2][b][u0]) << 32);
        st_hc8(xw1ring + (size_t)((slot * 32 + b) * 512 + uu) * 4, pv);
      } else {
        cb1 = f2bf(o_s1 + a1 * p_s1 + a2 * hn);
      }
    }
    asm volatile("s_waitcnt vmcnt(0)" ::: "memory");  // ring stores at coherence pt
    __syncthreads();
    if (tid == 0)
      __hip_atomic_store(flags + (role * FSTEPS + s) * 32 + g, 1,
                         __ATOMIC_RELAXED, __HIP_MEMORY_SCOPE_AGENT);
    // role2 HBM output AFTER publish: off the critical path
    if (role == 2){
      comb[((size_t)b0i * 1024 + t) * 512 + uu] = cb0;
      if (has1) comb[((size_t)b1i * 1024 + t) * 512 + uu] = cb1;
    }

    if (role == 0){
      xz0 = nz0; xr0 = nr0; xh0 = nh0;
      xz1 = nz1; xr1 = nr1; xh1 = nh1;
    }
  }
}

// ---------------------------------------------------------------------------
extern "C" void kernel_launch(void* const* d_in, const int* in_sizes, int n_in,
                              void* d_out, int out_size, void* d_ws, size_t ws_size,
                              hipStream_t stream)
{
  const float* x   = (const float*)d_in[0];
  const float* k0  = (const float*)d_in[1];
  const float* r0  = (const float*)d_in[2];
  const float* b0  = (const float*)d_in[3];
  const float* ks  = (const float*)d_in[4];
  const float* rs  = (const float*)d_in[5];
  const float* bs  = (const float*)d_in[6];
  const float* h00 = (const float*)d_in[7];
  const float* h01 = (const float*)d_in[8];
  const float* h02 = (const float*)d_in[9];
  const float* a   = (const float*)d_in[10];
  const float* wd  = (const float*)d_in[11];
  const float* bd  = (const float*)d_in[12];
  float* outp = (float*)d_out;

  // ws layout (bytes), ~142.8 MB total:
  //   [0,        100663296)  XW0   [32768,1536] bf16
  //   [100663296,134217728)  comb  [32768,512] bf16 (first 16.8MB aliases x_bf)
  //   [134217728,136577024)  rings (2.25 MB)
  //   [136577024,136973312)  flags [3][1032][32] int
  //   [136973312,...]        bf16 weights k0b,r0b,ksb,rsb,wdb
  char* ws = (char*)d_ws;
  ushort* XW    = (ushort*)(ws);
  ushort* combp = (ushort*)(ws + 100663296u);
  ushort* xbf   = combp;                      // alias: dead before rec3_k runs
  ushort* rings = (ushort*)(ws + 134217728u);
  int*    flags = (int*)   (ws + 136577024u);
  ushort* k0b   = (ushort*)(ws + 136973312u);
  ushort* r0b   = (ushort*)(ws + 137759744u);
  ushort* ksb   = (ushort*)(ws + 139332608u);
  ushort* rsb   = (ushort*)(ws + 140905472u);
  ushort* wdb   = (ushort*)(ws + 142478336u);

  hipMemsetAsync(flags, 0, 3 * FSTEPS * 32 * sizeof(int), stream);

  dim3 blk(256);
  cvt_k<<<dim3(8192), blk, 0, stream>>>(x,  xbf, 8388608);
  cvt_k<<<dim3(384),  blk, 0, stream>>>(k0, k0b, 393216);
  cvt_k<<<dim3(768),  blk, 0, stream>>>(r0, r0b, 786432);
  cvt_k<<<dim3(768),  blk, 0, stream>>>(ks, ksb, 786432);
  cvt_k<<<dim3(768),  blk, 0, stream>>>(rs, rsb, 786432);
  cvt_k<<<dim3(128),  blk, 0, stream>>>(wd, wdb, 131072);

  // Layer-0 input projection (bulk GEMM)
  gemm_bias_k<0><<<dim3(512 * 24), blk, 0, stream>>>(xbf, k0b, b0, XW, 32768, 1536, 256);
  // Fused pipelined 3-layer recurrence (de-lockstepped)
  rec3_k<<<dim3(NWG), dim3(384), 0, stream>>>(XW, r0b, ksb, rsb, b0, bs,
                                              h00, h01, h02, a, combp, rings, flags);
  // Final projection: comb @ wd + bd -> fp32 d_out
  gemm_bias_k<1><<<dim3(512 * 4), blk, 0, stream>>>(combp, wdb, bd, outp, 32768, 256, 512);
}